// Round 7
// baseline (425.714 us; speedup 1.0000x reference)
//
#include <hip/hip_runtime.h>
#include <hip/hip_bf16.h>

#define NN 100000
#define NE 1600000
#define NBKT 391          // dst>>8 buckets
#define BCAP 4608

typedef __hip_bfloat16 bf16;
typedef unsigned short u16;
typedef unsigned int u32;
typedef short bshort8 __attribute__((ext_vector_type(8)));
typedef float f32x4 __attribute__((ext_vector_type(4)));
typedef float f32x2 __attribute__((ext_vector_type(2)));

__device__ __forceinline__ float b2f_raw(u16 u) {
    unsigned int w = ((unsigned int)u) << 16;
    float f; __builtin_memcpy(&f, &w, 4); return f;
}
__device__ __forceinline__ float uplo(u32 u) {
    u32 w = u << 16; float f; __builtin_memcpy(&f, &w, 4); return f;
}
__device__ __forceinline__ float uphi(u32 u) {
    u32 w = u & 0xFFFF0000u; float f; __builtin_memcpy(&f, &w, 4); return f;
}
__device__ __forceinline__ u16 f2bu(float f) {
    bf16 h = __float2bfloat16(f); u16 u; __builtin_memcpy(&u, &h, 2); return u;
}
__device__ __forceinline__ float eluf(float x) { return x > 0.f ? x : __expf(x) - 1.f; }

#define LOG2E 1.4426950408889634f
#define LN2F  0.6931471805599453f

// canonical weight block offsets (f32 words)
#define OFF_ENC_W0 0
#define OFF_ENC_B0 192
#define OFF_ENC_W1 256
#define OFF_ENC_B1 4352
#define OFF_DEC_W0 4416
#define OFF_DEC_B0 8512
#define OFF_DEC_W1 8576
#define OFF_DEC_B1 8768
#define OFF_EW0    8832     // raw [2,195,64]
#define OFF_EB0    33792
#define OFF_EW1    33920
#define OFF_EB1    42112
#define OFF_NW0    42240
#define OFF_NB0    58624
#define OFF_NW1    58752
#define OFF_NB1    66944
#define OFF_WF     67072    // folded eW1@nW0_lo [2][64][64]
#define OFF_BFOLD  75264    // folded eb1@nW0_lo [2][64]
#define WBLK_WORDS 75392

// swz blob (u16 units)
#define SWZ_V   12288
#define SWZ_N0  24576
#define SWZ_N1  45056
#define SWZ_DC  53248
#define SWZ_ENC 57344
#define SWZ_U16 61440

// probe + gcursor zero (merged)
__global__ void probe_kernel(const u16* __restrict__ xr,
                             const unsigned int* __restrict__ er,
                             int* __restrict__ flags, int* __restrict__ gcursor) {
    int tid = threadIdx.x;
    gcursor[tid] = 0;           // blockDim = 512
    if (tid >= 64) return;
    int lane = tid;
    int wild = 0, oddnz = 0;
#pragma unroll
    for (int k = 0; k < 4; ++k) {
        int e = (xr[lane + k * 64] >> 7) & 0xFF;
        if (e > 140 || (e < 90 && e != 0)) wild++;
    }
#pragma unroll
    for (int k = 0; k < 2; ++k)
        if (er[1 + 2 * (lane + k * 64)] != 0u) oddnz++;
#pragma unroll
    for (int off = 32; off; off >>= 1) {
        wild += __shfl_down(wild, off);
        oddnz += __shfl_down(oddnz, off);
    }
    if (lane == 0) { flags[0] = (wild > 16) ? 1 : 0; flags[1] = (oddnz < 8) ? 1 : 0; }
}

struct WPtrs { const void* p[16]; };

__global__ void canon_weights(WPtrs wp, float* __restrict__ wblk,
                              const int* __restrict__ flags) {
    const int offs[16] = {OFF_ENC_W0, OFF_ENC_B0, OFF_ENC_W1, OFF_ENC_B1,
                          OFF_DEC_W0, OFF_DEC_B0, OFF_DEC_W1, OFF_DEC_B1,
                          OFF_EW0, OFF_EB0, OFF_EW1, OFF_EB1,
                          OFF_NW0, OFF_NB0, OFF_NW1, OFF_NB1};
    const int ns[16]   = {192, 64, 4096, 64, 4096, 64, 192, 3,
                          24960, 128, 8192, 128, 16384, 128, 8192, 128};
    int t = blockIdx.y;
    int i = blockIdx.x * blockDim.x + threadIdx.x;
    if (i >= ns[t]) return;
    const void* s = wp.p[t];
    float v = flags[0] ? ((const float*)s)[i] : b2f_raw(((const u16*)s)[i]);
    wblk[offs[t] + i] = v;
}

// Wf[l][k][c] = sum_m eW1[l][k][m]*nW0[l][64+m][c]; bfold[l][c] = sum_m eb1[l][m]*nW0[l][64+m][c]
__global__ void prep_wf(float* __restrict__ wblk) {
    int idx = blockIdx.x * 256 + threadIdx.x;
    if (idx < 8192) {
        int l = idx >> 12, r = idx & 4095, k = r >> 6, c = r & 63;
        const float* e1 = wblk + OFF_EW1 + l * 4096 + k * 64;
        const float* n0 = wblk + OFF_NW0 + l * 8192 + 64 * 64;
        float s = 0.f;
#pragma unroll 8
        for (int m = 0; m < 64; ++m) s += e1[m] * n0[m * 64 + c];
        wblk[OFF_WF + idx] = s;
    } else if (idx < 8320) {
        int i2 = idx - 8192;
        int l = i2 >> 6, c = i2 & 63;
        const float* b1 = wblk + OFF_EB1 + l * 64;
        const float* n0 = wblk + OFF_NW0 + l * 8192 + 64 * 64;
        float s = 0.f;
#pragma unroll 8
        for (int m = 0; m < 64; ++m) s += b1[m] * n0[m * 64 + c];
        wblk[OFF_BFOLD + i2] = s;
    }
}

// Pre-swizzle all MFMA B-blobs (bf16 fragment order).
__global__ void prep_swz(const float* __restrict__ wblk, u16* __restrict__ swz) {
    int t = blockIdx.x * 256 + threadIdx.x;
    if (t >= SWZ_U16) return;
    float v = 0.f;
    if (t < SWZ_N0) {                 // U-blob / V-blob: [2][3ks][4][64][8]
        int isV = (t >= SWZ_V);
        int t2 = isV ? t - SWZ_V : t;
        int l = t2 / 6144, r = t2 % 6144;
        int ks = r >> 11, nt = (r >> 9) & 3, lane = (r >> 3) & 63, j = r & 7;
        int k = ks * 32 + ((lane >> 4) & 3) * 8 + j;
        int n = nt * 16 + (lane & 15);
        const float* W = wblk + OFF_EW0 + l * 12480;
        if (k < 64)
            v = isV ? (W[(64 + k) * 64 + n] - W[(128 + k) * 64 + n])
                    : (W[k * 64 + n] + W[(128 + k) * 64 + n]);
        else if (k < 67) {
            v = W[(192 + (k - 64)) * 64 + n];
            if (isV) v = -v;
        }
    } else if (t < SWZ_N1) {          // node layer1 blob: [2][5ks][4][64][8]
        int t2 = t - SWZ_N0;
        int l = t2 / 10240, r = t2 % 10240;
        int ks = r >> 11, nt = (r >> 9) & 3, lane = (r >> 3) & 63, j = r & 7;
        int k = ks * 32 + ((lane >> 4) & 3) * 8 + j;
        int n = nt * 16 + (lane & 15);
        if (k < 64)        v = wblk[OFF_NW0 + l * 8192 + k * 64 + n];
        else if (k < 128)  v = wblk[OFF_WF + l * 4096 + (k - 64) * 64 + n];
        else if (k == 128) v = wblk[OFF_BFOLD + l * 64 + n];
    } else if (t < SWZ_DC) {          // node layer2 blob: [2][2ks][4][64][8]
        int t2 = t - SWZ_N1;
        int l = t2 / 4096, r = t2 % 4096;
        int ks = r >> 11, nt = (r >> 9) & 3, lane = (r >> 3) & 63, j = r & 7;
        int k = ks * 32 + ((lane >> 4) & 3) * 8 + j;
        int n = nt * 16 + (lane & 15);
        v = wblk[OFF_NW1 + l * 4096 + k * 64 + n];
    } else if (t < SWZ_ENC) {         // decoder W0 blob: [2ks][4][64][8]
        int r = t - SWZ_DC;
        int ks = r >> 11, nt = (r >> 9) & 3, lane = (r >> 3) & 63, j = r & 7;
        int k = ks * 32 + ((lane >> 4) & 3) * 8 + j;
        int n = nt * 16 + (lane & 15);
        v = wblk[OFF_DEC_W0 + k * 64 + n];
    } else {                          // encoder W1 blob: [2ks][4][64][8]
        int r = t - SWZ_ENC;
        int ks = r >> 11, nt = (r >> 9) & 3, lane = (r >> 3) & 63, j = r & 7;
        int k = ks * 32 + ((lane >> 4) & 3) * 8 + j;
        int n = nt * 16 + (lane & 15);
        v = wblk[OFF_ENC_W1 + k * 64 + n];
    }
    swz[t] = f2bu(v);
}

// ---- dst sort ---------------------------------------------------------------
__global__ __launch_bounds__(1024) void passA_bin(
    const void* __restrict__ eiraw, const int* __restrict__ flags,
    u32* __restrict__ epk_b, int* __restrict__ gcursor) {
    __shared__ int hist[NBKT];
    __shared__ int binstart[NBKT];
    __shared__ int gbase_l[NBKT];
    __shared__ int fill[NBKT];
    __shared__ int sc[512];
    __shared__ u32 stage[4096];
    __shared__ u16 slotbin[4096];
    int tid = threadIdx.x;
    for (int i = tid; i < NBKT; i += 1024) hist[i] = 0;
    __syncthreads();
    int base = blockIdx.x * 4096;
    int total = NE - base; if (total > 4096) total = 4096;
    bool i64 = flags[1] != 0;
    u32 ed[4]; int bn[4];
#pragma unroll
    for (int k = 0; k < 4; ++k) {
        int e = base + tid + k * 1024;
        bn[k] = -1;
        if (e < NE) {
            int s, d;
            if (i64) {
                s = (int)((const long long*)eiraw)[e];
                d = (int)((const long long*)eiraw)[(size_t)NE + e];
            } else {
                s = ((const int*)eiraw)[e];
                d = ((const int*)eiraw)[(size_t)NE + e];
            }
            if ((unsigned)s >= NN) s = 0;
            if ((unsigned)d >= NN) d = 0;
            ed[k] = (u32)s | ((u32)(d & 255) << 17);
            bn[k] = d >> 8;
            atomicAdd(&hist[bn[k]], 1);
        }
    }
    __syncthreads();
    if (tid < 512) sc[tid] = (tid < NBKT) ? hist[tid] : 0;
    __syncthreads();
    for (int d = 1; d < 512; d <<= 1) {
        int v = (tid >= d && tid < 512) ? sc[tid - d] : 0;
        __syncthreads();
        if (tid < 512) sc[tid] += v;
        __syncthreads();
    }
    if (tid < NBKT) {
        binstart[tid] = sc[tid] - hist[tid];
        fill[tid] = 0;
        gbase_l[tid] = hist[tid] ? atomicAdd(&gcursor[tid], hist[tid]) : 0;
    }
    __syncthreads();
#pragma unroll
    for (int k = 0; k < 4; ++k) {
        if (bn[k] >= 0) {
            int p = binstart[bn[k]] + atomicAdd(&fill[bn[k]], 1);
            stage[p] = ed[k];
            slotbin[p] = (u16)bn[k];
        }
    }
    __syncthreads();
    for (int i = tid; i < total; i += 1024) {
        int b = slotbin[i];
        int gp = gbase_l[b] + (i - binstart[b]);
        if (gp < BCAP) epk_b[(size_t)b * BCAP + gp] = stage[i];
    }
}

// srcs stores PRE-SHIFTED slice-row offsets (s << 2, u32 units of a 16B slice
// row). scan391 folded in (each block redundantly prefix-sums bucket counts).
__global__ __launch_bounds__(1024) void passB_sort(
    const u32* __restrict__ epk_b, const int* __restrict__ gcursor,
    int* __restrict__ srcs, int* __restrict__ start) {
    __shared__ int gsc[512];
    __shared__ int h256[256];
    __shared__ int off256[256];
    __shared__ int sc[256];
    __shared__ u32 stage[BCAP];
    int b = blockIdx.x, tid = threadIdx.x;
    if (tid < 512) {
        int v = 0;
        if (tid < NBKT) { v = gcursor[tid]; if (v > BCAP) v = BCAP; }
        gsc[tid] = v;
    }
    for (int i = tid; i < 256; i += 1024) h256[i] = 0;
    __syncthreads();
    for (int d = 1; d < 512; d <<= 1) {
        int u = (tid >= d && tid < 512) ? gsc[tid - d] : 0;
        __syncthreads();
        if (tid < 512) gsc[tid] += u;
        __syncthreads();
    }
    int cnt = gcursor[b]; if (cnt > BCAP) cnt = BCAP;
    int gb = gsc[b] - cnt;                 // exclusive prefix
    u32 ed[5]; int dl[5];
#pragma unroll
    for (int k = 0; k < 5; ++k) {
        int i = tid + k * 1024;
        dl[k] = -1;
        if (i < cnt) {
            ed[k] = epk_b[(size_t)b * BCAP + i];
            dl[k] = (int)(ed[k] >> 17);
            atomicAdd(&h256[dl[k]], 1);
        }
    }
    __syncthreads();
    if (tid < 256) sc[tid] = h256[tid];
    __syncthreads();
    for (int d = 1; d < 256; d <<= 1) {
        int v = (tid >= d && tid < 256) ? sc[tid - d] : 0;
        __syncthreads();
        if (tid < 256) sc[tid] += v;
        __syncthreads();
    }
    if (tid < 256) {
        off256[tid] = sc[tid] - h256[tid];
        start[b * 256 + tid] = gb + sc[tid] - h256[tid];
    }
    __syncthreads();
#pragma unroll
    for (int k = 0; k < 5; ++k) {
        if (dl[k] >= 0) {
            int p = atomicAdd(&off256[dl[k]], 1);
            stage[p] = ed[k];
        }
    }
    __syncthreads();
    for (int i = tid; i < cnt; i += 1024)
        srcs[gb + i] = (int)(stage[i] & 0x1FFFFu) << 2;
}
// ----------------------------------------------------------------------------

// U, V, Sb live in CHANNEL-SLICED layout: [8][NN][8ch] u16 (16B compact rows).
// Slice k holds channels 8k..8k+7. edge_sum block b (slice b&7) then gathers
// from one compact 1.6MB table -> fully resident in its XCD's 4MB L2.

// Fused encoder + UV(l=0); 512-thread blocks (8 waves share weight LDS).
// U,V written PRE-SCALED by log2e (edge_sum computes elu via exp2).
__global__ __launch_bounds__(512) void enc_uv(
    const void* __restrict__ xraw, const void* __restrict__ praw,
    const float* __restrict__ wblk, const u16* __restrict__ swzE,
    const u16* __restrict__ swzU, const u16* __restrict__ swzV,
    u16* __restrict__ hb, u16* __restrict__ pos4b,
    u16* __restrict__ U, u16* __restrict__ V,
    const int* __restrict__ flags) {
    __shared__ __attribute__((aligned(16))) u16 sE[4096];
    __shared__ __attribute__((aligned(16))) u16 sU[6144];
    __shared__ __attribute__((aligned(16))) u16 sV[6144];
    __shared__ __attribute__((aligned(16))) u16 sP[8][16 * 72];
    int tid = threadIdx.x;
    for (int i = tid; i < 512; i += 512) ((uint4*)sE)[i] = ((const uint4*)swzE)[i];
    for (int i = tid; i < 768; i += 512) {
        ((uint4*)sU)[i] = ((const uint4*)swzU)[i];
        ((uint4*)sV)[i] = ((const uint4*)swzV)[i];
    }
    __syncthreads();
    int wid = tid >> 6, lane = tid & 63;
    int m16 = lane & 15, half = lane >> 4;
    int g = blockIdx.x * 8 + wid;
    if (g >= NN / 16) return;
    int n0 = g * 16 + m16;
    bool isf = flags[0] != 0;
    float x0, x1, x2;
    if (isf) {
        x0 = ((const float*)xraw)[n0 * 3 + 0];
        x1 = ((const float*)xraw)[n0 * 3 + 1];
        x2 = ((const float*)xraw)[n0 * 3 + 2];
    } else {
        x0 = b2f_raw(((const u16*)xraw)[n0 * 3 + 0]);
        x1 = b2f_raw(((const u16*)xraw)[n0 * 3 + 1]);
        x2 = b2f_raw(((const u16*)xraw)[n0 * 3 + 2]);
    }
    u16 pk0 = 0, pk1 = 0, pk2 = 0;
    if (half == 0) {
        float p0 = isf ? ((const float*)praw)[n0 * 3 + 0] : b2f_raw(((const u16*)praw)[n0 * 3 + 0]);
        float p1 = isf ? ((const float*)praw)[n0 * 3 + 1] : b2f_raw(((const u16*)praw)[n0 * 3 + 1]);
        float p2 = isf ? ((const float*)praw)[n0 * 3 + 2] : b2f_raw(((const u16*)praw)[n0 * 3 + 2]);
        pk0 = f2bu(p0); pk1 = f2bu(p1); pk2 = f2bu(p2);
        *(ushort4*)(pos4b + (size_t)n0 * 4) = make_ushort4(pk0, pk1, pk2, 0);
    }
    const float* W0 = wblk + OFF_ENC_W0;
    const float* b0 = wblk + OFF_ENC_B0;
    bshort8 af0, af1;
#pragma unroll
    for (int j = 0; j < 8; ++j) {
        int c = half * 8 + j;
        float v = b0[c] + x0 * W0[c] + x1 * W0[64 + c] + x2 * W0[128 + c];
        af0[j] = (short)f2bu(eluf(v));
        int c2 = 32 + c;
        float v2 = b0[c2] + x0 * W0[c2] + x1 * W0[64 + c2] + x2 * W0[128 + c2];
        af1[j] = (short)f2bu(eluf(v2));
    }
    const bshort8* BE = (const bshort8*)sE;
    f32x4 acc[4];
#pragma unroll
    for (int nt = 0; nt < 4; ++nt) {
        float b = wblk[OFF_ENC_B1 + nt * 16 + m16];
        acc[nt] = f32x4{b, b, b, b};
    }
#pragma unroll
    for (int nt = 0; nt < 4; ++nt)
        acc[nt] = __builtin_amdgcn_mfma_f32_16x16x32_bf16(af0, BE[nt * 64 + lane], acc[nt], 0, 0, 0);
#pragma unroll
    for (int nt = 0; nt < 4; ++nt)
        acc[nt] = __builtin_amdgcn_mfma_f32_16x16x32_bf16(af1, BE[(4 + nt) * 64 + lane], acc[nt], 0, 0, 0);
    u16* myP = sP[wid];
#pragma unroll
    for (int nt = 0; nt < 4; ++nt)
#pragma unroll
        for (int r = 0; r < 4; ++r) {
            size_t ix = (size_t)(g * 16 + half * 4 + r) * 64 + nt * 16 + m16;
            u16 hv = f2bu(acc[nt][r]);
            hb[ix] = hv;
            myP[(half * 4 + r) * 72 + nt * 16 + m16] = hv;
        }
    bshort8 ah0 = *(const bshort8*)(myP + m16 * 72 + 0 * 32 + half * 8);
    bshort8 ah1 = *(const bshort8*)(myP + m16 * 72 + 1 * 32 + half * 8);
    bshort8 ap;
#pragma unroll
    for (int j = 0; j < 8; ++j) ap[j] = 0;
    if (half == 0) { ap[0] = (short)pk0; ap[1] = (short)pk1; ap[2] = (short)pk2; }
    const bshort8* BU = (const bshort8*)sU;
    const bshort8* BV = (const bshort8*)sV;
    const float* eb0p = wblk + OFF_EB0;   // l = 0
    f32x4 aU[4], aV[4];
#pragma unroll
    for (int nt = 0; nt < 4; ++nt) {
        float bv = eb0p[nt * 16 + m16];
        aU[nt] = f32x4{0.f, 0.f, 0.f, 0.f};
        aV[nt] = f32x4{bv, bv, bv, bv};
    }
#pragma unroll
    for (int nt = 0; nt < 4; ++nt) {
        aU[nt] = __builtin_amdgcn_mfma_f32_16x16x32_bf16(ah0, BU[nt * 64 + lane], aU[nt], 0, 0, 0);
        aV[nt] = __builtin_amdgcn_mfma_f32_16x16x32_bf16(ah0, BV[nt * 64 + lane], aV[nt], 0, 0, 0);
    }
#pragma unroll
    for (int nt = 0; nt < 4; ++nt) {
        aU[nt] = __builtin_amdgcn_mfma_f32_16x16x32_bf16(ah1, BU[(4 + nt) * 64 + lane], aU[nt], 0, 0, 0);
        aV[nt] = __builtin_amdgcn_mfma_f32_16x16x32_bf16(ah1, BV[(4 + nt) * 64 + lane], aV[nt], 0, 0, 0);
    }
#pragma unroll
    for (int nt = 0; nt < 4; ++nt) {
        aU[nt] = __builtin_amdgcn_mfma_f32_16x16x32_bf16(ap, BU[(8 + nt) * 64 + lane], aU[nt], 0, 0, 0);
        aV[nt] = __builtin_amdgcn_mfma_f32_16x16x32_bf16(ap, BV[(8 + nt) * 64 + lane], aV[nt], 0, 0, 0);
    }
    // sliced stores: channel c -> slice c>>3, offset (slice*NN + node)*8 + (c&7)
#pragma unroll
    for (int nt = 0; nt < 4; ++nt)
#pragma unroll
        for (int r = 0; r < 4; ++r) {
            int node = g * 16 + half * 4 + r;
            int c = nt * 16 + m16;
            size_t ix = ((size_t)(c >> 3) * NN + node) * 8 + (c & 7);
            U[ix] = f2bu(aU[nt][r] * LOG2E);
            V[ix] = f2bu(aV[nt][r] * LOG2E);
        }
}

// Edge sum v8 — XCD-sliced compact gather:
//  - U/V/Sb in [8][NN][8ch] layout; block b owns slice b&7; with round-robin
//    block->XCD dispatch each XCD gathers only its own 1.6MB compact table
//    (L2-resident; was 31% hit on the 12.8MB interleaved table)
//  - lane = (eo 0..15, co 0..3): gather = dword (2ch) at row src + co;
//    one gather instr covers 16 edges
//  - cross-node prefetch of next node's first-32 srcs + V row
//  - elu-sum via prescaled exp2: S = ln2*sum(max(x,0)) + sum(min(2^x,1)) - deg
__global__ __launch_bounds__(256, 8) void edge_sum(
    const u32* __restrict__ U32, const u32* __restrict__ V32,
    const int* __restrict__ srcs, const int* __restrict__ start,
    u32* __restrict__ Sb, int totalranges) {
    int tid = threadIdx.x;
    int b = blockIdx.x;
    int s = b & 7;                       // slice == XCD (perf heuristic only)
    int w = (b >> 3) * 4 + (tid >> 6);   // node-range id
    int lane = tid & 63;
    int eo = lane >> 2, co = lane & 3;
    const u32* Ub = U32 + (size_t)s * NN * 4;
    const u32* Vb = V32 + (size_t)s * NN * 4;
    u32* Sbb = Sb + (size_t)s * NN * 4;
    int nb = (int)((long long)w * NN / totalranges);
    int ne = (int)((long long)(w + 1) * NN / totalranges);
    if (nb >= ne) return;

    int s0 = start[nb];
    int s1 = start[nb + 1];
    // prefetch node nb: first (up to) 32 edges' srcs + V slice-row
    // (overreads stay inside the workspace; masked before use as offsets)
    int pf0 = srcs[s0 + eo];
    int pf1 = srcs[s0 + 16 + eo];
    u32 pvw = Vb[(u32)nb * 4 + (u32)co];

    const f32x2 z2 = {0.f, 0.f}, o2 = {1.f, 1.f};

    for (int n = nb; n < ne; ++n) {
        int cnt = s1 - s0;
        int c0 = pf0, c1 = pf1;
        u32 vw = pvw;
        int s0n = s1;
        int s1n = start[n + 2];   // start has NN+512 entries
        {
            int vn = (n + 1 < NN) ? (n + 1) : (NN - 1);
            pf0 = srcs[s0n + eo];
            pf1 = srcs[s0n + 16 + eo];
            pvw = Vb[(u32)vn * 4 + (u32)co];
        }

        f32x2 v01 = {uplo(vw), uphi(vw)};
        f32x2 aA = z2, aB = z2;

        auto gat = [&](u32 spre) -> u32 { return Ub[spre + (u32)co]; };
        auto body = [&](u32 uw) {
            f32x2 x = f32x2{uplo(uw), uphi(uw)} + v01;
            f32x2 e = {__builtin_amdgcn_exp2f(x.x), __builtin_amdgcn_exp2f(x.y)};
            aA += __builtin_elementwise_max(x, z2);
            aB += __builtin_elementwise_min(e, o2);
        };
        auto bodym = [&](u32 uw, bool val) {
            f32x2 x = f32x2{uplo(uw), uphi(uw)} + v01;
            f32x2 e = {__builtin_amdgcn_exp2f(x.x), __builtin_amdgcn_exp2f(x.y)};
            f32x2 mA = __builtin_elementwise_max(x, z2);
            f32x2 mB = __builtin_elementwise_min(e, o2);
            aA += val ? mA : z2;
            aB += val ? mB : z2;
        };

        if (cnt >= 32) {
            u32 u0 = gat((u32)c0), u1 = gat((u32)c1);
            body(u0); body(u1);
            int g = 32;
            for (; g + 16 <= cnt; g += 16) {
                int a = srcs[s0 + g + eo];
                body(gat((u32)a));
            }
            if (g < cnt) {
                int a = srcs[s0 + g + eo];
                bool m = eo < (cnt - g);
                bodym(gat(m ? (u32)a : 0u), m);
            }
        } else if (cnt > 16) {
            bool m = eo < (cnt - 16);
            u32 u0 = gat((u32)c0);
            u32 u1 = gat(m ? (u32)c1 : 0u);
            body(u0); bodym(u1, m);
        } else if (cnt > 0) {
            bool m = eo < cnt;
            bodym(gat(m ? (u32)c0 : 0u), m);
        }

        // fold before cross-lane reduce: t = ln2*aA + aB; sum over 16 eo groups
        f32x2 t = aA * LN2F + aB;
        float t0 = t.x, t1 = t.y;
        t0 += __shfl_xor(t0, 4);  t1 += __shfl_xor(t1, 4);
        t0 += __shfl_xor(t0, 8);  t1 += __shfl_xor(t1, 8);
        t0 += __shfl_xor(t0, 16); t1 += __shfl_xor(t1, 16);
        t0 += __shfl_xor(t0, 32); t1 += __shfl_xor(t1, 32);
        if (eo == 0) {
            float cf = (float)cnt;
            Sbb[(u32)n * 4 + (u32)co] = (u32)f2bu(t0 - cf) | ((u32)f2bu(t1 - cf) << 16);
        }
        s0 = s0n; s1 = s1n;
    }
}

// Fused node MLP l=0 + UV(l=1); 512-thread blocks (8 waves share weight LDS).
// Sb read from sliced layout; U,V written sliced, PRE-SCALED by log2e.
__global__ __launch_bounds__(512) void node_uv(
    u16* __restrict__ hb, const u16* __restrict__ Sb,
    const int* __restrict__ start, const float* __restrict__ wblk,
    const u16* __restrict__ swz, const u16* __restrict__ pos4b,
    u16* __restrict__ U, u16* __restrict__ V) {
    __shared__ __attribute__((aligned(16))) u16 sN0[10240];
    __shared__ __attribute__((aligned(16))) u16 sN1[4096];
    __shared__ __attribute__((aligned(16))) u16 sU[6144];
    __shared__ __attribute__((aligned(16))) u16 sV[6144];
    __shared__ __attribute__((aligned(16))) u16 sP[8][16 * 72];
    int tid = threadIdx.x;
    {
        const uint4* s0 = (const uint4*)(swz + SWZ_N0);
        const uint4* s1 = (const uint4*)(swz + SWZ_N1);
        const uint4* su = (const uint4*)(swz + 6144);
        const uint4* sv = (const uint4*)(swz + SWZ_V + 6144);
        for (int i = tid; i < 1280; i += 512) ((uint4*)sN0)[i] = s0[i];
        for (int i = tid; i < 512; i += 512)  ((uint4*)sN1)[i] = s1[i];
        for (int i = tid; i < 768; i += 512) {
            ((uint4*)sU)[i] = su[i];
            ((uint4*)sV)[i] = sv[i];
        }
    }
    __syncthreads();
    int wid = tid >> 6, lane = tid & 63;
    int m16 = lane & 15, half = lane >> 4;
    int g = blockIdx.x * 8 + wid;
    if (g >= NN / 16) return;
    int n0 = g * 16 + m16;
    const float* b0 = wblk + OFF_NB0;
    const float* b1 = wblk + OFF_NB1;
    const bshort8* B0 = (const bshort8*)sN0;
    const bshort8* B1 = (const bshort8*)sN1;
    u16* myP = sP[wid];

    bshort8 afh0 = *(const bshort8*)(hb + (size_t)n0 * 64 + half * 8);
    bshort8 afh1 = *(const bshort8*)(hb + (size_t)n0 * 64 + 32 + half * 8);
    // sliced Sb: afs0 = channels half*8..+7 = slice half; afs1 = slice 4+half
    bshort8 afs0 = *(const bshort8*)(Sb + ((size_t)half * NN + n0) * 8);
    bshort8 afs1 = *(const bshort8*)(Sb + ((size_t)(4 + half) * NN + n0) * 8);
    bshort8 afd;
#pragma unroll
    for (int j = 0; j < 8; ++j) afd[j] = 0;
    if (half == 0) {
        float deg = (float)(start[n0 + 1] - start[n0]);
        afd[0] = (short)f2bu(deg);
    }
    f32x4 acc[4];
#pragma unroll
    for (int nt = 0; nt < 4; ++nt) {
        float b = b0[nt * 16 + m16];
        acc[nt] = f32x4{b, b, b, b};
    }
#pragma unroll
    for (int nt = 0; nt < 4; ++nt)
        acc[nt] = __builtin_amdgcn_mfma_f32_16x16x32_bf16(afh0, B0[nt * 64 + lane], acc[nt], 0, 0, 0);
#pragma unroll
    for (int nt = 0; nt < 4; ++nt)
        acc[nt] = __builtin_amdgcn_mfma_f32_16x16x32_bf16(afh1, B0[(4 + nt) * 64 + lane], acc[nt], 0, 0, 0);
#pragma unroll
    for (int nt = 0; nt < 4; ++nt)
        acc[nt] = __builtin_amdgcn_mfma_f32_16x16x32_bf16(afs0, B0[(8 + nt) * 64 + lane], acc[nt], 0, 0, 0);
#pragma unroll
    for (int nt = 0; nt < 4; ++nt)
        acc[nt] = __builtin_amdgcn_mfma_f32_16x16x32_bf16(afs1, B0[(12 + nt) * 64 + lane], acc[nt], 0, 0, 0);
#pragma unroll
    for (int nt = 0; nt < 4; ++nt)
        acc[nt] = __builtin_amdgcn_mfma_f32_16x16x32_bf16(afd, B0[(16 + nt) * 64 + lane], acc[nt], 0, 0, 0);
#pragma unroll
    for (int nt = 0; nt < 4; ++nt)
#pragma unroll
        for (int r = 0; r < 4; ++r) {
            float v = acc[nt][r];
            v = eluf(v);
            myP[(half * 4 + r) * 72 + nt * 16 + m16] = f2bu(v);
        }
    f32x4 acc2[4];
#pragma unroll
    for (int nt = 0; nt < 4; ++nt) {
        float b = b1[nt * 16 + m16];
        acc2[nt] = f32x4{b, b, b, b};
    }
#pragma unroll
    for (int ks = 0; ks < 2; ++ks) {
        bshort8 av = *(const bshort8*)(myP + m16 * 72 + ks * 32 + half * 8);
#pragma unroll
        for (int nt = 0; nt < 4; ++nt)
            acc2[nt] = __builtin_amdgcn_mfma_f32_16x16x32_bf16(
                av, B1[(ks * 4 + nt) * 64 + lane], acc2[nt], 0, 0, 0);
    }
    // residual (bf16 h) + store + transpose nh for UV
#pragma unroll
    for (int nt = 0; nt < 4; ++nt)
#pragma unroll
        for (int r = 0; r < 4; ++r) {
            size_t ix = (size_t)(g * 16 + half * 4 + r) * 64 + nt * 16 + m16;
            float v = b2f_raw(hb[ix]) + acc2[nt][r];
            u16 hv = f2bu(v);
            hb[ix] = hv;
            myP[(half * 4 + r) * 72 + nt * 16 + m16] = hv;
        }
    bshort8 ah0 = *(const bshort8*)(myP + m16 * 72 + 0 * 32 + half * 8);
    bshort8 ah1 = *(const bshort8*)(myP + m16 * 72 + 1 * 32 + half * 8);
    bshort8 ap;
#pragma unroll
    for (int j = 0; j < 8; ++j) ap[j] = 0;
    if (half == 0) {
        ushort4 pp = *(const ushort4*)(pos4b + (size_t)n0 * 4);
        ap[0] = (short)pp.x; ap[1] = (short)pp.y; ap[2] = (short)pp.z;
    }
    const bshort8* BU = (const bshort8*)sU;
    const bshort8* BV = (const bshort8*)sV;
    const float* eb0p = wblk + OFF_EB0 + 64;   // l = 1
    f32x4 aU[4], aV[4];
#pragma unroll
    for (int nt = 0; nt < 4; ++nt) {
        float bv = eb0p[nt * 16 + m16];
        aU[nt] = f32x4{0.f, 0.f, 0.f, 0.f};
        aV[nt] = f32x4{bv, bv, bv, bv};
    }
#pragma unroll
    for (int nt = 0; nt < 4; ++nt) {
        aU[nt] = __builtin_amdgcn_mfma_f32_16x16x32_bf16(ah0, BU[nt * 64 + lane], aU[nt], 0, 0, 0);
        aV[nt] = __builtin_amdgcn_mfma_f32_16x16x32_bf16(ah0, BV[nt * 64 + lane], aV[nt], 0, 0, 0);
    }
#pragma unroll
    for (int nt = 0; nt < 4; ++nt) {
        aU[nt] = __builtin_amdgcn_mfma_f32_16x16x32_bf16(ah1, BU[(4 + nt) * 64 + lane], aU[nt], 0, 0, 0);
        aV[nt] = __builtin_amdgcn_mfma_f32_16x16x32_bf16(ah1, BV[(4 + nt) * 64 + lane], aV[nt], 0, 0, 0);
    }
#pragma unroll
    for (int nt = 0; nt < 4; ++nt) {
        aU[nt] = __builtin_amdgcn_mfma_f32_16x16x32_bf16(ap, BU[(8 + nt) * 64 + lane], aU[nt], 0, 0, 0);
        aV[nt] = __builtin_amdgcn_mfma_f32_16x16x32_bf16(ap, BV[(8 + nt) * 64 + lane], aV[nt], 0, 0, 0);
    }
#pragma unroll
    for (int nt = 0; nt < 4; ++nt)
#pragma unroll
        for (int r = 0; r < 4; ++r) {
            int node = g * 16 + half * 4 + r;
            int c = nt * 16 + m16;
            size_t ix = ((size_t)(c >> 3) * NN + node) * 8 + (c & 7);
            U[ix] = f2bu(aU[nt][r] * LOG2E);
            V[ix] = f2bu(aV[nt][r] * LOG2E);
        }
}

// node MLP l=1 + residual + fused decoder; 512-thread blocks.
__global__ __launch_bounds__(512) void node_dec(
    const u16* __restrict__ hb, const u16* __restrict__ Sb,
    const int* __restrict__ start, const float* __restrict__ wblk,
    const u16* __restrict__ swz,
    void* __restrict__ out, const int* __restrict__ flags) {
    __shared__ __attribute__((aligned(16))) u16 sN0[10240];
    __shared__ __attribute__((aligned(16))) u16 sN1[4096];
    __shared__ __attribute__((aligned(16))) u16 sDec[4096];
    __shared__ __attribute__((aligned(16))) float sT[8][1048];
    int tid = threadIdx.x;
    {
        const uint4* s0 = (const uint4*)(swz + SWZ_N0 + 10240);
        const uint4* s1 = (const uint4*)(swz + SWZ_N1 + 4096);
        const uint4* sd = (const uint4*)(swz + SWZ_DC);
        for (int i = tid; i < 1280; i += 512) ((uint4*)sN0)[i] = s0[i];
        for (int i = tid; i < 512; i += 512)  ((uint4*)sN1)[i] = s1[i];
        for (int i = tid; i < 512; i += 512)  ((uint4*)sDec)[i] = sd[i];
    }
    __syncthreads();
    int wid = tid >> 6, lane = tid & 63;
    int m16 = lane & 15, half = lane >> 4;
    int g = blockIdx.x * 8 + wid;
    if (g >= NN / 16) return;
    int n0 = g * 16 + m16;
    const float* b0 = wblk + OFF_NB0 + 64;
    const float* b1 = wblk + OFF_NB1 + 64;
    const bshort8* B0 = (const bshort8*)sN0;
    const bshort8* B1 = (const bshort8*)sN1;
    const bshort8* BD = (const bshort8*)sDec;
    u16* myP = (u16*)sT[wid];
    float* sD = sT[wid];

    bshort8 afh0 = *(const bshort8*)(hb + (size_t)n0 * 64 + half * 8);
    bshort8 afh1 = *(const bshort8*)(hb + (size_t)n0 * 64 + 32 + half * 8);
    bshort8 afs0 = *(const bshort8*)(Sb + ((size_t)half * NN + n0) * 8);
    bshort8 afs1 = *(const bshort8*)(Sb + ((size_t)(4 + half) * NN + n0) * 8);
    bshort8 afd;
#pragma unroll
    for (int j = 0; j < 8; ++j) afd[j] = 0;
    if (half == 0) {
        float deg = (float)(start[n0 + 1] - start[n0]);
        afd[0] = (short)f2bu(deg);
    }
    f32x4 acc[4];
#pragma unroll
    for (int nt = 0; nt < 4; ++nt) {
        float b = b0[nt * 16 + m16];
        acc[nt] = f32x4{b, b, b, b};
    }
#pragma unroll
    for (int nt = 0; nt < 4; ++nt)
        acc[nt] = __builtin_amdgcn_mfma_f32_16x16x32_bf16(afh0, B0[nt * 64 + lane], acc[nt], 0, 0, 0);
#pragma unroll
    for (int nt = 0; nt < 4; ++nt)
        acc[nt] = __builtin_amdgcn_mfma_f32_16x16x32_bf16(afh1, B0[(4 + nt) * 64 + lane], acc[nt], 0, 0, 0);
#pragma unroll
    for (int nt = 0; nt < 4; ++nt)
        acc[nt] = __builtin_amdgcn_mfma_f32_16x16x32_bf16(afs0, B0[(8 + nt) * 64 + lane], acc[nt], 0, 0, 0);
#pragma unroll
    for (int nt = 0; nt < 4; ++nt)
        acc[nt] = __builtin_amdgcn_mfma_f32_16x16x32_bf16(afs1, B0[(12 + nt) * 64 + lane], acc[nt], 0, 0, 0);
#pragma unroll
    for (int nt = 0; nt < 4; ++nt)
        acc[nt] = __builtin_amdgcn_mfma_f32_16x16x32_bf16(afd, B0[(16 + nt) * 64 + lane], acc[nt], 0, 0, 0);
#pragma unroll
    for (int nt = 0; nt < 4; ++nt)
#pragma unroll
        for (int r = 0; r < 4; ++r) {
            float v = acc[nt][r];
            v = eluf(v);
            myP[(half * 4 + r) * 72 + nt * 16 + m16] = f2bu(v);
        }
    f32x4 acc2[4];
#pragma unroll
    for (int nt = 0; nt < 4; ++nt) {
        float b = b1[nt * 16 + m16];
        acc2[nt] = f32x4{b, b, b, b};
    }
#pragma unroll
    for (int ks = 0; ks < 2; ++ks) {
        bshort8 av = *(const bshort8*)(myP + m16 * 72 + ks * 32 + half * 8);
#pragma unroll
        for (int nt = 0; nt < 4; ++nt)
            acc2[nt] = __builtin_amdgcn_mfma_f32_16x16x32_bf16(
                av, B1[(ks * 4 + nt) * 64 + lane], acc2[nt], 0, 0, 0);
    }
    float nh[4][4];
#pragma unroll
    for (int nt = 0; nt < 4; ++nt)
#pragma unroll
        for (int r = 0; r < 4; ++r) {
            size_t ix = (size_t)(g * 16 + half * 4 + r) * 64 + nt * 16 + m16;
            nh[nt][r] = b2f_raw(hb[ix]) + acc2[nt][r];
        }
#pragma unroll
    for (int nt = 0; nt < 4; ++nt)
#pragma unroll
        for (int r = 0; r < 4; ++r)
            myP[(half * 4 + r) * 72 + nt * 16 + m16] = f2bu(nh[nt][r]);
    const float* db0 = wblk + OFF_DEC_B0;
    f32x4 acc3[4];
#pragma unroll
    for (int nt = 0; nt < 4; ++nt) {
        float b = db0[nt * 16 + m16];
        acc3[nt] = f32x4{b, b, b, b};
    }
#pragma unroll
    for (int ks = 0; ks < 2; ++ks) {
        bshort8 av = *(const bshort8*)(myP + m16 * 72 + ks * 32 + half * 8);
#pragma unroll
        for (int nt = 0; nt < 4; ++nt)
            acc3[nt] = __builtin_amdgcn_mfma_f32_16x16x32_bf16(
                av, BD[(ks * 4 + nt) * 64 + lane], acc3[nt], 0, 0, 0);
    }
#pragma unroll
    for (int nt = 0; nt < 4; ++nt)
#pragma unroll
        for (int r = 0; r < 4; ++r) {
            float v = acc3[nt][r];
            v = eluf(v);
            sD[(half * 4 + r) * 65 + nt * 16 + m16] = v;
        }
    if (lane < 48) {
        int j = lane / 3, o = lane - j * 3;
        const float* dW1 = wblk + OFF_DEC_W1;
        float oacc = wblk[OFF_DEC_B1 + o];
#pragma unroll
        for (int k = 0; k < 64; ++k) oacc += sD[j * 65 + k] * dW1[k * 3 + o];
        int nn = g * 16 + j;
        if (flags[0]) ((float*)out)[nn * 3 + o] = oacc;
        else          ((bf16*)out)[nn * 3 + o] = __float2bfloat16(oacc);
    }
}

extern "C" void kernel_launch(void* const* d_in, const int* in_sizes, int n_in,
                              void* d_out, int out_size, void* d_ws, size_t ws_size,
                              hipStream_t stream) {
    // Workspace (f32 words), total ~59 MB
    int*   flags   = (int*)d_ws;                        // 16
    float* wblk    = (float*)d_ws + 16;                 // 75392
    u16*   swz     = (u16*)(wblk + WBLK_WORDS);         // 61440 u16
    u16*   pos4b   = swz + SWZ_U16;                     // 400000 u16
    int*   gcursor = (int*)(pos4b + 400000);            // 512
    int*   gbase2  = gcursor + 512;                     // 512 (unused, layout kept)
    int*   start   = gbase2 + 512;                      // NN + 512
    int*   srcs    = start + NN + 512;                  // NE
    u16*   Sb      = (u16*)(srcs + NE);                 // NN*64 u16 (12.8 MB)
    u16*   hb      = Sb + (size_t)NN * 64;              // NN*64 u16 (12.8 MB)
    u16*   U       = hb + (size_t)NN * 64;              // NN*64 u16
    u16*   V       = U + (size_t)NN * 64;               // NN*64 u16
    u32*   epk_b   = (u32*)Sb;  // 391*4608 u32 = 7.2MB <= Sb 12.8MB; dead before edge_sum

    probe_kernel<<<1, 512, 0, stream>>>((const u16*)d_in[0],
                                        (const unsigned int*)d_in[2], flags, gcursor);

    WPtrs wp;
    wp.p[0] = d_in[3];  wp.p[1] = d_in[4];  wp.p[2] = d_in[5];  wp.p[3] = d_in[6];
    wp.p[4] = d_in[7];  wp.p[5] = d_in[8];  wp.p[6] = d_in[9];  wp.p[7] = d_in[10];
    wp.p[8] = d_in[11]; wp.p[9] = d_in[12]; wp.p[10] = d_in[13]; wp.p[11] = d_in[14];
    wp.p[12] = d_in[15]; wp.p[13] = d_in[16]; wp.p[14] = d_in[17]; wp.p[15] = d_in[18];
    canon_weights<<<dim3(98, 16), 256, 0, stream>>>(wp, wblk, flags);
    prep_wf<<<33, 256, 0, stream>>>(wblk);
    prep_swz<<<240, 256, 0, stream>>>(wblk, swz);

    passA_bin<<<(NE + 4095) / 4096, 1024, 0, stream>>>(d_in[2], flags, epk_b, gcursor);
    passB_sort<<<NBKT, 1024, 0, stream>>>(epk_b, gcursor, srcs, start);

    const int NODE_BLOCKS = (NN / 16 + 7) / 8;   // 782 (8 waves per block)
    const int EDGE_BLOCKS = 2048;                // 256 per XCD-slice
    const int TOTALRANGES = (EDGE_BLOCKS / 8) * 4;  // 1024 node ranges

    enc_uv<<<NODE_BLOCKS, 512, 0, stream>>>(
        d_in[0], d_in[1], wblk, swz + SWZ_ENC,
        swz, swz + SWZ_V, hb, pos4b, U, V, flags);

    // layer 0
    edge_sum<<<EDGE_BLOCKS, 256, 0, stream>>>(
        (const u32*)U, (const u32*)V, srcs, start, (u32*)Sb, TOTALRANGES);
    node_uv<<<NODE_BLOCKS, 512, 0, stream>>>(
        hb, Sb, start, wblk, swz, pos4b, U, V);

    // layer 1
    edge_sum<<<EDGE_BLOCKS, 256, 0, stream>>>(
        (const u32*)U, (const u32*)V, srcs, start, (u32*)Sb, TOTALRANGES);
    node_dec<<<NODE_BLOCKS, 512, 0, stream>>>(
        hb, Sb, start, wblk, swz, d_out, flags);
}

// Round 8
// 301.796 us; speedup vs baseline: 1.4106x; 1.4106x over previous
//
#include <hip/hip_runtime.h>
#include <hip/hip_bf16.h>

#define NN 100000
#define NE 1600000
#define NBKT 391          // dst>>8 buckets
#define BCAP 4608

typedef __hip_bfloat16 bf16;
typedef unsigned short u16;
typedef unsigned int u32;
typedef short bshort8 __attribute__((ext_vector_type(8)));
typedef float f32x4 __attribute__((ext_vector_type(4)));
typedef float f32x2 __attribute__((ext_vector_type(2)));

__device__ __forceinline__ float b2f_raw(u16 u) {
    unsigned int w = ((unsigned int)u) << 16;
    float f; __builtin_memcpy(&f, &w, 4); return f;
}
__device__ __forceinline__ float uplo(u32 u) {
    u32 w = u << 16; float f; __builtin_memcpy(&f, &w, 4); return f;
}
__device__ __forceinline__ float uphi(u32 u) {
    u32 w = u & 0xFFFF0000u; float f; __builtin_memcpy(&f, &w, 4); return f;
}
__device__ __forceinline__ u16 f2bu(float f) {
    bf16 h = __float2bfloat16(f); u16 u; __builtin_memcpy(&u, &h, 2); return u;
}
__device__ __forceinline__ float eluf(float x) { return x > 0.f ? x : __expf(x) - 1.f; }
__device__ __forceinline__ int4 ld4(const int* p) {
    int4 v; __builtin_memcpy(&v, p, 16); return v;
}

#define LOG2E 1.4426950408889634f
#define LN2F  0.6931471805599453f

// canonical weight block offsets (f32 words)
#define OFF_ENC_W0 0
#define OFF_ENC_B0 192
#define OFF_ENC_W1 256
#define OFF_ENC_B1 4352
#define OFF_DEC_W0 4416
#define OFF_DEC_B0 8512
#define OFF_DEC_W1 8576
#define OFF_DEC_B1 8768
#define OFF_EW0    8832     // raw [2,195,64]
#define OFF_EB0    33792
#define OFF_EW1    33920
#define OFF_EB1    42112
#define OFF_NW0    42240
#define OFF_NB0    58624
#define OFF_NW1    58752
#define OFF_NB1    66944
#define OFF_WF     67072    // folded eW1@nW0_lo [2][64][64]
#define OFF_BFOLD  75264    // folded eb1@nW0_lo [2][64]
#define WBLK_WORDS 75392

// swz blob (u16 units)
#define SWZ_V   12288
#define SWZ_N0  24576
#define SWZ_N1  45056
#define SWZ_DC  53248
#define SWZ_ENC 57344
#define SWZ_U16 61440

// probe + gcursor zero (merged)
__global__ void probe_kernel(const u16* __restrict__ xr,
                             const unsigned int* __restrict__ er,
                             int* __restrict__ flags, int* __restrict__ gcursor) {
    int tid = threadIdx.x;
    gcursor[tid] = 0;           // blockDim = 512
    if (tid >= 64) return;
    int lane = tid;
    int wild = 0, oddnz = 0;
#pragma unroll
    for (int k = 0; k < 4; ++k) {
        int e = (xr[lane + k * 64] >> 7) & 0xFF;
        if (e > 140 || (e < 90 && e != 0)) wild++;
    }
#pragma unroll
    for (int k = 0; k < 2; ++k)
        if (er[1 + 2 * (lane + k * 64)] != 0u) oddnz++;
#pragma unroll
    for (int off = 32; off; off >>= 1) {
        wild += __shfl_down(wild, off);
        oddnz += __shfl_down(oddnz, off);
    }
    if (lane == 0) { flags[0] = (wild > 16) ? 1 : 0; flags[1] = (oddnz < 8) ? 1 : 0; }
}

struct WPtrs { const void* p[16]; };

__global__ void canon_weights(WPtrs wp, float* __restrict__ wblk,
                              const int* __restrict__ flags) {
    const int offs[16] = {OFF_ENC_W0, OFF_ENC_B0, OFF_ENC_W1, OFF_ENC_B1,
                          OFF_DEC_W0, OFF_DEC_B0, OFF_DEC_W1, OFF_DEC_B1,
                          OFF_EW0, OFF_EB0, OFF_EW1, OFF_EB1,
                          OFF_NW0, OFF_NB0, OFF_NW1, OFF_NB1};
    const int ns[16]   = {192, 64, 4096, 64, 4096, 64, 192, 3,
                          24960, 128, 8192, 128, 16384, 128, 8192, 128};
    int t = blockIdx.y;
    int i = blockIdx.x * blockDim.x + threadIdx.x;
    if (i >= ns[t]) return;
    const void* s = wp.p[t];
    float v = flags[0] ? ((const float*)s)[i] : b2f_raw(((const u16*)s)[i]);
    wblk[offs[t] + i] = v;
}

// Wf[l][k][c] = sum_m eW1[l][k][m]*nW0[l][64+m][c]; bfold[l][c] = sum_m eb1[l][m]*nW0[l][64+m][c]
__global__ void prep_wf(float* __restrict__ wblk) {
    int idx = blockIdx.x * 256 + threadIdx.x;
    if (idx < 8192) {
        int l = idx >> 12, r = idx & 4095, k = r >> 6, c = r & 63;
        const float* e1 = wblk + OFF_EW1 + l * 4096 + k * 64;
        const float* n0 = wblk + OFF_NW0 + l * 8192 + 64 * 64;
        float s = 0.f;
#pragma unroll 8
        for (int m = 0; m < 64; ++m) s += e1[m] * n0[m * 64 + c];
        wblk[OFF_WF + idx] = s;
    } else if (idx < 8320) {
        int i2 = idx - 8192;
        int l = i2 >> 6, c = i2 & 63;
        const float* b1 = wblk + OFF_EB1 + l * 64;
        const float* n0 = wblk + OFF_NW0 + l * 8192 + 64 * 64;
        float s = 0.f;
#pragma unroll 8
        for (int m = 0; m < 64; ++m) s += b1[m] * n0[m * 64 + c];
        wblk[OFF_BFOLD + i2] = s;
    }
}

// Pre-swizzle all MFMA B-blobs (bf16 fragment order).
__global__ void prep_swz(const float* __restrict__ wblk, u16* __restrict__ swz) {
    int t = blockIdx.x * 256 + threadIdx.x;
    if (t >= SWZ_U16) return;
    float v = 0.f;
    if (t < SWZ_N0) {                 // U-blob / V-blob: [2][3ks][4][64][8]
        int isV = (t >= SWZ_V);
        int t2 = isV ? t - SWZ_V : t;
        int l = t2 / 6144, r = t2 % 6144;
        int ks = r >> 11, nt = (r >> 9) & 3, lane = (r >> 3) & 63, j = r & 7;
        int k = ks * 32 + ((lane >> 4) & 3) * 8 + j;
        int n = nt * 16 + (lane & 15);
        const float* W = wblk + OFF_EW0 + l * 12480;
        if (k < 64)
            v = isV ? (W[(64 + k) * 64 + n] - W[(128 + k) * 64 + n])
                    : (W[k * 64 + n] + W[(128 + k) * 64 + n]);
        else if (k < 67) {
            v = W[(192 + (k - 64)) * 64 + n];
            if (isV) v = -v;
        }
    } else if (t < SWZ_N1) {          // node layer1 blob: [2][5ks][4][64][8]
        int t2 = t - SWZ_N0;
        int l = t2 / 10240, r = t2 % 10240;
        int ks = r >> 11, nt = (r >> 9) & 3, lane = (r >> 3) & 63, j = r & 7;
        int k = ks * 32 + ((lane >> 4) & 3) * 8 + j;
        int n = nt * 16 + (lane & 15);
        if (k < 64)        v = wblk[OFF_NW0 + l * 8192 + k * 64 + n];
        else if (k < 128)  v = wblk[OFF_WF + l * 4096 + (k - 64) * 64 + n];
        else if (k == 128) v = wblk[OFF_BFOLD + l * 64 + n];
    } else if (t < SWZ_DC) {          // node layer2 blob: [2][2ks][4][64][8]
        int t2 = t - SWZ_N1;
        int l = t2 / 4096, r = t2 % 4096;
        int ks = r >> 11, nt = (r >> 9) & 3, lane = (r >> 3) & 63, j = r & 7;
        int k = ks * 32 + ((lane >> 4) & 3) * 8 + j;
        int n = nt * 16 + (lane & 15);
        v = wblk[OFF_NW1 + l * 4096 + k * 64 + n];
    } else if (t < SWZ_ENC) {         // decoder W0 blob: [2ks][4][64][8]
        int r = t - SWZ_DC;
        int ks = r >> 11, nt = (r >> 9) & 3, lane = (r >> 3) & 63, j = r & 7;
        int k = ks * 32 + ((lane >> 4) & 3) * 8 + j;
        int n = nt * 16 + (lane & 15);
        v = wblk[OFF_DEC_W0 + k * 64 + n];
    } else {                          // encoder W1 blob: [2ks][4][64][8]
        int r = t - SWZ_ENC;
        int ks = r >> 11, nt = (r >> 9) & 3, lane = (r >> 3) & 63, j = r & 7;
        int k = ks * 32 + ((lane >> 4) & 3) * 8 + j;
        int n = nt * 16 + (lane & 15);
        v = wblk[OFF_ENC_W1 + k * 64 + n];
    }
    swz[t] = f2bu(v);
}

// ---- dst sort ---------------------------------------------------------------
__global__ __launch_bounds__(1024) void passA_bin(
    const void* __restrict__ eiraw, const int* __restrict__ flags,
    u32* __restrict__ epk_b, int* __restrict__ gcursor) {
    __shared__ int hist[NBKT];
    __shared__ int binstart[NBKT];
    __shared__ int gbase_l[NBKT];
    __shared__ int fill[NBKT];
    __shared__ int sc[512];
    __shared__ u32 stage[4096];
    __shared__ u16 slotbin[4096];
    int tid = threadIdx.x;
    for (int i = tid; i < NBKT; i += 1024) hist[i] = 0;
    __syncthreads();
    int base = blockIdx.x * 4096;
    int total = NE - base; if (total > 4096) total = 4096;
    bool i64 = flags[1] != 0;
    u32 ed[4]; int bn[4];
#pragma unroll
    for (int k = 0; k < 4; ++k) {
        int e = base + tid + k * 1024;
        bn[k] = -1;
        if (e < NE) {
            int s, d;
            if (i64) {
                s = (int)((const long long*)eiraw)[e];
                d = (int)((const long long*)eiraw)[(size_t)NE + e];
            } else {
                s = ((const int*)eiraw)[e];
                d = ((const int*)eiraw)[(size_t)NE + e];
            }
            if ((unsigned)s >= NN) s = 0;
            if ((unsigned)d >= NN) d = 0;
            ed[k] = (u32)s | ((u32)(d & 255) << 17);
            bn[k] = d >> 8;
            atomicAdd(&hist[bn[k]], 1);
        }
    }
    __syncthreads();
    if (tid < 512) sc[tid] = (tid < NBKT) ? hist[tid] : 0;
    __syncthreads();
    for (int d = 1; d < 512; d <<= 1) {
        int v = (tid >= d && tid < 512) ? sc[tid - d] : 0;
        __syncthreads();
        if (tid < 512) sc[tid] += v;
        __syncthreads();
    }
    if (tid < NBKT) {
        binstart[tid] = sc[tid] - hist[tid];
        fill[tid] = 0;
        gbase_l[tid] = hist[tid] ? atomicAdd(&gcursor[tid], hist[tid]) : 0;
    }
    __syncthreads();
#pragma unroll
    for (int k = 0; k < 4; ++k) {
        if (bn[k] >= 0) {
            int p = binstart[bn[k]] + atomicAdd(&fill[bn[k]], 1);
            stage[p] = ed[k];
            slotbin[p] = (u16)bn[k];
        }
    }
    __syncthreads();
    for (int i = tid; i < total; i += 1024) {
        int b = slotbin[i];
        int gp = gbase_l[b] + (i - binstart[b]);
        if (gp < BCAP) epk_b[(size_t)b * BCAP + gp] = stage[i];
    }
}

// srcs stores PRE-SHIFTED row offsets (s << 5, u32 units of a 64-ch bf16 row).
// scan391 folded in: each block redundantly prefix-sums the 391 clamped bucket
// counts in LDS (~0.4us, concurrent) -> one fewer kernel launch (R6 win kept).
__global__ __launch_bounds__(1024) void passB_sort(
    const u32* __restrict__ epk_b, const int* __restrict__ gcursor,
    int* __restrict__ srcs, int* __restrict__ start) {
    __shared__ int gsc[512];
    __shared__ int h256[256];
    __shared__ int off256[256];
    __shared__ int sc[256];
    __shared__ u32 stage[BCAP];
    int b = blockIdx.x, tid = threadIdx.x;
    if (tid < 512) {
        int v = 0;
        if (tid < NBKT) { v = gcursor[tid]; if (v > BCAP) v = BCAP; }
        gsc[tid] = v;
    }
    for (int i = tid; i < 256; i += 1024) h256[i] = 0;
    __syncthreads();
    for (int d = 1; d < 512; d <<= 1) {
        int u = (tid >= d && tid < 512) ? gsc[tid - d] : 0;
        __syncthreads();
        if (tid < 512) gsc[tid] += u;
        __syncthreads();
    }
    int cnt = gcursor[b]; if (cnt > BCAP) cnt = BCAP;
    int gb = gsc[b] - cnt;                 // exclusive prefix
    u32 ed[5]; int dl[5];
#pragma unroll
    for (int k = 0; k < 5; ++k) {
        int i = tid + k * 1024;
        dl[k] = -1;
        if (i < cnt) {
            ed[k] = epk_b[(size_t)b * BCAP + i];
            dl[k] = (int)(ed[k] >> 17);
            atomicAdd(&h256[dl[k]], 1);
        }
    }
    __syncthreads();
    if (tid < 256) sc[tid] = h256[tid];
    __syncthreads();
    for (int d = 1; d < 256; d <<= 1) {
        int v = (tid >= d && tid < 256) ? sc[tid - d] : 0;
        __syncthreads();
        if (tid < 256) sc[tid] += v;
        __syncthreads();
    }
    if (tid < 256) {
        off256[tid] = sc[tid] - h256[tid];
        start[b * 256 + tid] = gb + sc[tid] - h256[tid];
    }
    __syncthreads();
#pragma unroll
    for (int k = 0; k < 5; ++k) {
        if (dl[k] >= 0) {
            int p = atomicAdd(&off256[dl[k]], 1);
            stage[p] = ed[k];
        }
    }
    __syncthreads();
    for (int i = tid; i < cnt; i += 1024)
        srcs[gb + i] = (int)(stage[i] & 0x1FFFFu) << 5;
}
// ----------------------------------------------------------------------------

// Fused encoder + UV(l=0); 512-thread blocks (8 waves share weight LDS).
// U,V written PRE-SCALED by log2e (edge_sum computes elu via exp2).
__global__ __launch_bounds__(512) void enc_uv(
    const void* __restrict__ xraw, const void* __restrict__ praw,
    const float* __restrict__ wblk, const u16* __restrict__ swzE,
    const u16* __restrict__ swzU, const u16* __restrict__ swzV,
    u16* __restrict__ hb, u16* __restrict__ pos4b,
    u16* __restrict__ U, u16* __restrict__ V,
    const int* __restrict__ flags) {
    __shared__ __attribute__((aligned(16))) u16 sE[4096];
    __shared__ __attribute__((aligned(16))) u16 sU[6144];
    __shared__ __attribute__((aligned(16))) u16 sV[6144];
    __shared__ __attribute__((aligned(16))) u16 sP[8][16 * 72];
    int tid = threadIdx.x;
    for (int i = tid; i < 512; i += 512) ((uint4*)sE)[i] = ((const uint4*)swzE)[i];
    for (int i = tid; i < 768; i += 512) {
        ((uint4*)sU)[i] = ((const uint4*)swzU)[i];
        ((uint4*)sV)[i] = ((const uint4*)swzV)[i];
    }
    __syncthreads();
    int wid = tid >> 6, lane = tid & 63;
    int m16 = lane & 15, half = lane >> 4;
    int g = blockIdx.x * 8 + wid;
    if (g >= NN / 16) return;
    int n0 = g * 16 + m16;
    bool isf = flags[0] != 0;
    float x0, x1, x2;
    if (isf) {
        x0 = ((const float*)xraw)[n0 * 3 + 0];
        x1 = ((const float*)xraw)[n0 * 3 + 1];
        x2 = ((const float*)xraw)[n0 * 3 + 2];
    } else {
        x0 = b2f_raw(((const u16*)xraw)[n0 * 3 + 0]);
        x1 = b2f_raw(((const u16*)xraw)[n0 * 3 + 1]);
        x2 = b2f_raw(((const u16*)xraw)[n0 * 3 + 2]);
    }
    u16 pk0 = 0, pk1 = 0, pk2 = 0;
    if (half == 0) {
        float p0 = isf ? ((const float*)praw)[n0 * 3 + 0] : b2f_raw(((const u16*)praw)[n0 * 3 + 0]);
        float p1 = isf ? ((const float*)praw)[n0 * 3 + 1] : b2f_raw(((const u16*)praw)[n0 * 3 + 1]);
        float p2 = isf ? ((const float*)praw)[n0 * 3 + 2] : b2f_raw(((const u16*)praw)[n0 * 3 + 2]);
        pk0 = f2bu(p0); pk1 = f2bu(p1); pk2 = f2bu(p2);
        *(ushort4*)(pos4b + (size_t)n0 * 4) = make_ushort4(pk0, pk1, pk2, 0);
    }
    const float* W0 = wblk + OFF_ENC_W0;
    const float* b0 = wblk + OFF_ENC_B0;
    bshort8 af0, af1;
#pragma unroll
    for (int j = 0; j < 8; ++j) {
        int c = half * 8 + j;
        float v = b0[c] + x0 * W0[c] + x1 * W0[64 + c] + x2 * W0[128 + c];
        af0[j] = (short)f2bu(eluf(v));
        int c2 = 32 + c;
        float v2 = b0[c2] + x0 * W0[c2] + x1 * W0[64 + c2] + x2 * W0[128 + c2];
        af1[j] = (short)f2bu(eluf(v2));
    }
    const bshort8* BE = (const bshort8*)sE;
    f32x4 acc[4];
#pragma unroll
    for (int nt = 0; nt < 4; ++nt) {
        float b = wblk[OFF_ENC_B1 + nt * 16 + m16];
        acc[nt] = f32x4{b, b, b, b};
    }
#pragma unroll
    for (int nt = 0; nt < 4; ++nt)
        acc[nt] = __builtin_amdgcn_mfma_f32_16x16x32_bf16(af0, BE[nt * 64 + lane], acc[nt], 0, 0, 0);
#pragma unroll
    for (int nt = 0; nt < 4; ++nt)
        acc[nt] = __builtin_amdgcn_mfma_f32_16x16x32_bf16(af1, BE[(4 + nt) * 64 + lane], acc[nt], 0, 0, 0);
    u16* myP = sP[wid];
#pragma unroll
    for (int nt = 0; nt < 4; ++nt)
#pragma unroll
        for (int r = 0; r < 4; ++r) {
            size_t ix = (size_t)(g * 16 + half * 4 + r) * 64 + nt * 16 + m16;
            u16 hv = f2bu(acc[nt][r]);
            hb[ix] = hv;
            myP[(half * 4 + r) * 72 + nt * 16 + m16] = hv;
        }
    bshort8 ah0 = *(const bshort8*)(myP + m16 * 72 + 0 * 32 + half * 8);
    bshort8 ah1 = *(const bshort8*)(myP + m16 * 72 + 1 * 32 + half * 8);
    bshort8 ap;
#pragma unroll
    for (int j = 0; j < 8; ++j) ap[j] = 0;
    if (half == 0) { ap[0] = (short)pk0; ap[1] = (short)pk1; ap[2] = (short)pk2; }
    const bshort8* BU = (const bshort8*)sU;
    const bshort8* BV = (const bshort8*)sV;
    const float* eb0p = wblk + OFF_EB0;   // l = 0
    f32x4 aU[4], aV[4];
#pragma unroll
    for (int nt = 0; nt < 4; ++nt) {
        float bv = eb0p[nt * 16 + m16];
        aU[nt] = f32x4{0.f, 0.f, 0.f, 0.f};
        aV[nt] = f32x4{bv, bv, bv, bv};
    }
#pragma unroll
    for (int nt = 0; nt < 4; ++nt) {
        aU[nt] = __builtin_amdgcn_mfma_f32_16x16x32_bf16(ah0, BU[nt * 64 + lane], aU[nt], 0, 0, 0);
        aV[nt] = __builtin_amdgcn_mfma_f32_16x16x32_bf16(ah0, BV[nt * 64 + lane], aV[nt], 0, 0, 0);
    }
#pragma unroll
    for (int nt = 0; nt < 4; ++nt) {
        aU[nt] = __builtin_amdgcn_mfma_f32_16x16x32_bf16(ah1, BU[(4 + nt) * 64 + lane], aU[nt], 0, 0, 0);
        aV[nt] = __builtin_amdgcn_mfma_f32_16x16x32_bf16(ah1, BV[(4 + nt) * 64 + lane], aV[nt], 0, 0, 0);
    }
#pragma unroll
    for (int nt = 0; nt < 4; ++nt) {
        aU[nt] = __builtin_amdgcn_mfma_f32_16x16x32_bf16(ap, BU[(8 + nt) * 64 + lane], aU[nt], 0, 0, 0);
        aV[nt] = __builtin_amdgcn_mfma_f32_16x16x32_bf16(ap, BV[(8 + nt) * 64 + lane], aV[nt], 0, 0, 0);
    }
#pragma unroll
    for (int nt = 0; nt < 4; ++nt)
#pragma unroll
        for (int r = 0; r < 4; ++r) {
            size_t ix = (size_t)(g * 16 + half * 4 + r) * 64 + nt * 16 + m16;
            U[ix] = f2bu(aU[nt][r] * LOG2E);
            V[ix] = f2bu(aV[nt][r] * LOG2E);
        }
}

// Edge sum (R4 structure — session best):
//  - lane = (eo 0..3, co 0..15); lane eo owns edges 4eo..4eo+3 of each group
//  - srcs pre-shifted (<<5) in passB: gather voffset = spre + coff
//  - 32-edge prefetch of NEXT node (2x dwordx4 + V row) before current compute
//  - elu-sum via prescaled exp2: S = ln2*sum(max(x,0)) + sum(min(2^x,1)) - deg
__global__ __launch_bounds__(256, 4) void edge_sum(
    const u32* __restrict__ U32, const u32* __restrict__ V32,
    const int* __restrict__ srcs, const int* __restrict__ start,
    u32* __restrict__ Sb, int totalwaves) {
    int tid = threadIdx.x;
    int w = blockIdx.x * 4 + (tid >> 6);
    int lane = tid & 63;
    int eo = lane >> 4, co = lane & 15;
    u32 coff = (u32)(co << 1);
    int e0 = eo << 2;                 // first owned edge within a group
    int nb = (int)((long long)w * NN / totalwaves);
    int ne = (int)((long long)(w + 1) * NN / totalwaves);
    if (nb >= ne) return;

    int s0 = start[nb];
    int s1 = start[nb + 1];
    // prefetch node nb: first (up to) 32 edges' srcs + V row
    // (reads up to 31 past the node's end stay within the workspace; values
    //  are masked before use as gather offsets when cnt < 32)
    int4 pfa = ld4(srcs + s0 + e0);
    int4 pfb = ld4(srcs + s0 + 16 + e0);
    uint2 pv = *(const uint2*)(V32 + (((u32)nb << 5) + coff));

    const f32x2 z2 = {0.f, 0.f}, o2 = {1.f, 1.f};

    for (int n = nb; n < ne; ++n) {
        int cnt = s1 - s0;
        int4 ca = pfa, cb = pfb;
        uint2 vv = pv;
        int s0n = s1;
        int s1n = start[n + 2];   // start has NN+512 entries; used only if n+1<ne
        // prefetch next node (loads overlap current node's gathers/compute)
        {
            int vn = (n + 1 < NN) ? (n + 1) : (NN - 1);
            pfa = ld4(srcs + s0n + e0);
            pfb = ld4(srcs + s0n + 16 + e0);
            pv = *(const uint2*)(V32 + (((u32)vn << 5) + coff));
        }

        f32x2 v01 = {uplo(vv.x), uphi(vv.x)};
        f32x2 v23 = {uplo(vv.y), uphi(vv.y)};
        f32x2 aA01 = z2, aA23 = z2, aB01 = z2, aB23 = z2;

        auto gat = [&](int spre) -> uint2 {
            return *(const uint2*)(U32 + ((u32)spre + coff));
        };
        auto body = [&](uint2 uu) {
            f32x2 x01 = f32x2{uplo(uu.x), uphi(uu.x)} + v01;
            f32x2 x23 = f32x2{uplo(uu.y), uphi(uu.y)} + v23;
            f32x2 e01 = {__builtin_amdgcn_exp2f(x01.x), __builtin_amdgcn_exp2f(x01.y)};
            f32x2 e23 = {__builtin_amdgcn_exp2f(x23.x), __builtin_amdgcn_exp2f(x23.y)};
            aA01 += __builtin_elementwise_max(x01, z2);
            aA23 += __builtin_elementwise_max(x23, z2);
            aB01 += __builtin_elementwise_min(e01, o2);
            aB23 += __builtin_elementwise_min(e23, o2);
        };
        auto bodym = [&](uint2 uu, bool val) {
            f32x2 x01 = f32x2{uplo(uu.x), uphi(uu.x)} + v01;
            f32x2 x23 = f32x2{uplo(uu.y), uphi(uu.y)} + v23;
            f32x2 e01 = {__builtin_amdgcn_exp2f(x01.x), __builtin_amdgcn_exp2f(x01.y)};
            f32x2 e23 = {__builtin_amdgcn_exp2f(x23.x), __builtin_amdgcn_exp2f(x23.y)};
            f32x2 mA01 = __builtin_elementwise_max(x01, z2);
            f32x2 mA23 = __builtin_elementwise_max(x23, z2);
            f32x2 mB01 = __builtin_elementwise_min(e01, o2);
            f32x2 mB23 = __builtin_elementwise_min(e23, o2);
            aA01 += val ? mA01 : z2;
            aA23 += val ? mA23 : z2;
            aB01 += val ? mB01 : z2;
            aB23 += val ? mB23 : z2;
        };

        if (cnt >= 32) {
            // both prefetched groups unmasked; 8 gathers in flight
            uint2 u0 = gat(ca.x), u1 = gat(ca.y), u2 = gat(ca.z), u3 = gat(ca.w);
            uint2 u4 = gat(cb.x), u5 = gat(cb.y), u6 = gat(cb.z), u7 = gat(cb.w);
            body(u0); body(u1); body(u2); body(u3);
            body(u4); body(u5); body(u6); body(u7);
            int g = 32;
            for (; g + 16 <= cnt; g += 16) {
                int4 cc = ld4(srcs + s0 + g + e0);
                uint2 w0 = gat(cc.x), w1 = gat(cc.y), w2 = gat(cc.z), w3 = gat(cc.w);
                body(w0); body(w1); body(w2); body(w3);
            }
            if (g < cnt) {
                int4 cc = ld4(srcs + s0 + g + e0);
                int r = cnt - g;
                bool m0 = (e0 < r), m1 = (e0 + 1 < r), m2 = (e0 + 2 < r), m3 = (e0 + 3 < r);
                uint2 w0 = gat(m0 ? cc.x : 0), w1 = gat(m1 ? cc.y : 0);
                uint2 w2 = gat(m2 ? cc.z : 0), w3 = gat(m3 ? cc.w : 0);
                bodym(w0, m0); bodym(w1, m1); bodym(w2, m2); bodym(w3, m3);
            }
        } else if (cnt > 16) {
            int r = cnt - 16;
            bool m0 = (e0 < r), m1 = (e0 + 1 < r), m2 = (e0 + 2 < r), m3 = (e0 + 3 < r);
            uint2 u0 = gat(ca.x), u1 = gat(ca.y), u2 = gat(ca.z), u3 = gat(ca.w);
            uint2 u4 = gat(m0 ? cb.x : 0), u5 = gat(m1 ? cb.y : 0);
            uint2 u6 = gat(m2 ? cb.z : 0), u7 = gat(m3 ? cb.w : 0);
            body(u0); body(u1); body(u2); body(u3);
            bodym(u4, m0); bodym(u5, m1); bodym(u6, m2); bodym(u7, m3);
        } else if (cnt > 0) {
            bool m0 = (e0 < cnt), m1 = (e0 + 1 < cnt), m2 = (e0 + 2 < cnt), m3 = (e0 + 3 < cnt);
            uint2 u0 = gat(m0 ? ca.x : 0), u1 = gat(m1 ? ca.y : 0);
            uint2 u2 = gat(m2 ? ca.z : 0), u3 = gat(m3 ? ca.w : 0);
            bodym(u0, m0); bodym(u1, m1); bodym(u2, m2); bodym(u3, m3);
        }

        // fold before cross-lane reduce: t = ln2*aA + aB
        f32x2 t01 = aA01 * LN2F + aB01;
        f32x2 t23 = aA23 * LN2F + aB23;
        float t0 = t01.x, t1 = t01.y, t2 = t23.x, t3 = t23.y;
        t0 += __shfl_xor(t0, 16); t0 += __shfl_xor(t0, 32);
        t1 += __shfl_xor(t1, 16); t1 += __shfl_xor(t1, 32);
        t2 += __shfl_xor(t2, 16); t2 += __shfl_xor(t2, 32);
        t3 += __shfl_xor(t3, 16); t3 += __shfl_xor(t3, 32);
        if (eo == 0) {
            float cf = (float)cnt;
            u32 p0 = (u32)f2bu(t0 - cf) | ((u32)f2bu(t1 - cf) << 16);
            u32 p1 = (u32)f2bu(t2 - cf) | ((u32)f2bu(t3 - cf) << 16);
            *(uint2*)(Sb + (((u32)n << 5) + coff)) = make_uint2(p0, p1);
        }
        s0 = s0n; s1 = s1n;
    }
}

// Fused node MLP l=0 + UV(l=1); 512-thread blocks (8 waves share weight LDS).
// U,V written PRE-SCALED by log2e.
__global__ __launch_bounds__(512) void node_uv(
    u16* __restrict__ hb, const u16* __restrict__ Sb,
    const int* __restrict__ start, const float* __restrict__ wblk,
    const u16* __restrict__ swz, const u16* __restrict__ pos4b,
    u16* __restrict__ U, u16* __restrict__ V) {
    __shared__ __attribute__((aligned(16))) u16 sN0[10240];
    __shared__ __attribute__((aligned(16))) u16 sN1[4096];
    __shared__ __attribute__((aligned(16))) u16 sU[6144];
    __shared__ __attribute__((aligned(16))) u16 sV[6144];
    __shared__ __attribute__((aligned(16))) u16 sP[8][16 * 72];
    int tid = threadIdx.x;
    {
        const uint4* s0 = (const uint4*)(swz + SWZ_N0);
        const uint4* s1 = (const uint4*)(swz + SWZ_N1);
        const uint4* su = (const uint4*)(swz + 6144);
        const uint4* sv = (const uint4*)(swz + SWZ_V + 6144);
        for (int i = tid; i < 1280; i += 512) ((uint4*)sN0)[i] = s0[i];
        for (int i = tid; i < 512; i += 512)  ((uint4*)sN1)[i] = s1[i];
        for (int i = tid; i < 768; i += 512) {
            ((uint4*)sU)[i] = su[i];
            ((uint4*)sV)[i] = sv[i];
        }
    }
    __syncthreads();
    int wid = tid >> 6, lane = tid & 63;
    int m16 = lane & 15, half = lane >> 4;
    int g = blockIdx.x * 8 + wid;
    if (g >= NN / 16) return;
    int n0 = g * 16 + m16;
    const float* b0 = wblk + OFF_NB0;
    const float* b1 = wblk + OFF_NB1;
    const bshort8* B0 = (const bshort8*)sN0;
    const bshort8* B1 = (const bshort8*)sN1;
    u16* myP = sP[wid];

    bshort8 afh0 = *(const bshort8*)(hb + (size_t)n0 * 64 + half * 8);
    bshort8 afh1 = *(const bshort8*)(hb + (size_t)n0 * 64 + 32 + half * 8);
    bshort8 afs0 = *(const bshort8*)(Sb + (size_t)n0 * 64 + half * 8);
    bshort8 afs1 = *(const bshort8*)(Sb + (size_t)n0 * 64 + 32 + half * 8);
    bshort8 afd;
#pragma unroll
    for (int j = 0; j < 8; ++j) afd[j] = 0;
    if (half == 0) {
        float deg = (float)(start[n0 + 1] - start[n0]);
        afd[0] = (short)f2bu(deg);
    }
    f32x4 acc[4];
#pragma unroll
    for (int nt = 0; nt < 4; ++nt) {
        float b = b0[nt * 16 + m16];
        acc[nt] = f32x4{b, b, b, b};
    }
#pragma unroll
    for (int nt = 0; nt < 4; ++nt)
        acc[nt] = __builtin_amdgcn_mfma_f32_16x16x32_bf16(afh0, B0[nt * 64 + lane], acc[nt], 0, 0, 0);
#pragma unroll
    for (int nt = 0; nt < 4; ++nt)
        acc[nt] = __builtin_amdgcn_mfma_f32_16x16x32_bf16(afh1, B0[(4 + nt) * 64 + lane], acc[nt], 0, 0, 0);
#pragma unroll
    for (int nt = 0; nt < 4; ++nt)
        acc[nt] = __builtin_amdgcn_mfma_f32_16x16x32_bf16(afs0, B0[(8 + nt) * 64 + lane], acc[nt], 0, 0, 0);
#pragma unroll
    for (int nt = 0; nt < 4; ++nt)
        acc[nt] = __builtin_amdgcn_mfma_f32_16x16x32_bf16(afs1, B0[(12 + nt) * 64 + lane], acc[nt], 0, 0, 0);
#pragma unroll
    for (int nt = 0; nt < 4; ++nt)
        acc[nt] = __builtin_amdgcn_mfma_f32_16x16x32_bf16(afd, B0[(16 + nt) * 64 + lane], acc[nt], 0, 0, 0);
#pragma unroll
    for (int nt = 0; nt < 4; ++nt)
#pragma unroll
        for (int r = 0; r < 4; ++r) {
            float v = acc[nt][r];
            v = eluf(v);
            myP[(half * 4 + r) * 72 + nt * 16 + m16] = f2bu(v);
        }
    f32x4 acc2[4];
#pragma unroll
    for (int nt = 0; nt < 4; ++nt) {
        float b = b1[nt * 16 + m16];
        acc2[nt] = f32x4{b, b, b, b};
    }
#pragma unroll
    for (int ks = 0; ks < 2; ++ks) {
        bshort8 av = *(const bshort8*)(myP + m16 * 72 + ks * 32 + half * 8);
#pragma unroll
        for (int nt = 0; nt < 4; ++nt)
            acc2[nt] = __builtin_amdgcn_mfma_f32_16x16x32_bf16(
                av, B1[(ks * 4 + nt) * 64 + lane], acc2[nt], 0, 0, 0);
    }
    // residual (bf16 h) + store + transpose nh for UV
#pragma unroll
    for (int nt = 0; nt < 4; ++nt)
#pragma unroll
        for (int r = 0; r < 4; ++r) {
            size_t ix = (size_t)(g * 16 + half * 4 + r) * 64 + nt * 16 + m16;
            float v = b2f_raw(hb[ix]) + acc2[nt][r];
            u16 hv = f2bu(v);
            hb[ix] = hv;
            myP[(half * 4 + r) * 72 + nt * 16 + m16] = hv;
        }
    bshort8 ah0 = *(const bshort8*)(myP + m16 * 72 + 0 * 32 + half * 8);
    bshort8 ah1 = *(const bshort8*)(myP + m16 * 72 + 1 * 32 + half * 8);
    bshort8 ap;
#pragma unroll
    for (int j = 0; j < 8; ++j) ap[j] = 0;
    if (half == 0) {
        ushort4 pp = *(const ushort4*)(pos4b + (size_t)n0 * 4);
        ap[0] = (short)pp.x; ap[1] = (short)pp.y; ap[2] = (short)pp.z;
    }
    const bshort8* BU = (const bshort8*)sU;
    const bshort8* BV = (const bshort8*)sV;
    const float* eb0p = wblk + OFF_EB0 + 64;   // l = 1
    f32x4 aU[4], aV[4];
#pragma unroll
    for (int nt = 0; nt < 4; ++nt) {
        float bv = eb0p[nt * 16 + m16];
        aU[nt] = f32x4{0.f, 0.f, 0.f, 0.f};
        aV[nt] = f32x4{bv, bv, bv, bv};
    }
#pragma unroll
    for (int nt = 0; nt < 4; ++nt) {
        aU[nt] = __builtin_amdgcn_mfma_f32_16x16x32_bf16(ah0, BU[nt * 64 + lane], aU[nt], 0, 0, 0);
        aV[nt] = __builtin_amdgcn_mfma_f32_16x16x32_bf16(ah0, BV[nt * 64 + lane], aV[nt], 0, 0, 0);
    }
#pragma unroll
    for (int nt = 0; nt < 4; ++nt) {
        aU[nt] = __builtin_amdgcn_mfma_f32_16x16x32_bf16(ah1, BU[(4 + nt) * 64 + lane], aU[nt], 0, 0, 0);
        aV[nt] = __builtin_amdgcn_mfma_f32_16x16x32_bf16(ah1, BV[(4 + nt) * 64 + lane], aV[nt], 0, 0, 0);
    }
#pragma unroll
    for (int nt = 0; nt < 4; ++nt) {
        aU[nt] = __builtin_amdgcn_mfma_f32_16x16x32_bf16(ap, BU[(8 + nt) * 64 + lane], aU[nt], 0, 0, 0);
        aV[nt] = __builtin_amdgcn_mfma_f32_16x16x32_bf16(ap, BV[(8 + nt) * 64 + lane], aV[nt], 0, 0, 0);
    }
#pragma unroll
    for (int nt = 0; nt < 4; ++nt)
#pragma unroll
        for (int r = 0; r < 4; ++r) {
            size_t ix = (size_t)(g * 16 + half * 4 + r) * 64 + nt * 16 + m16;
            U[ix] = f2bu(aU[nt][r] * LOG2E);
            V[ix] = f2bu(aV[nt][r] * LOG2E);
        }
}

// node MLP l=1 + residual + fused decoder; 512-thread blocks.
__global__ __launch_bounds__(512) void node_dec(
    const u16* __restrict__ hb, const u16* __restrict__ Sb,
    const int* __restrict__ start, const float* __restrict__ wblk,
    const u16* __restrict__ swz,
    void* __restrict__ out, const int* __restrict__ flags) {
    __shared__ __attribute__((aligned(16))) u16 sN0[10240];
    __shared__ __attribute__((aligned(16))) u16 sN1[4096];
    __shared__ __attribute__((aligned(16))) u16 sDec[4096];
    __shared__ __attribute__((aligned(16))) float sT[8][1048];
    int tid = threadIdx.x;
    {
        const uint4* s0 = (const uint4*)(swz + SWZ_N0 + 10240);
        const uint4* s1 = (const uint4*)(swz + SWZ_N1 + 4096);
        const uint4* sd = (const uint4*)(swz + SWZ_DC);
        for (int i = tid; i < 1280; i += 512) ((uint4*)sN0)[i] = s0[i];
        for (int i = tid; i < 512; i += 512)  ((uint4*)sN1)[i] = s1[i];
        for (int i = tid; i < 512; i += 512)  ((uint4*)sDec)[i] = sd[i];
    }
    __syncthreads();
    int wid = tid >> 6, lane = tid & 63;
    int m16 = lane & 15, half = lane >> 4;
    int g = blockIdx.x * 8 + wid;
    if (g >= NN / 16) return;
    int n0 = g * 16 + m16;
    const float* b0 = wblk + OFF_NB0 + 64;
    const float* b1 = wblk + OFF_NB1 + 64;
    const bshort8* B0 = (const bshort8*)sN0;
    const bshort8* B1 = (const bshort8*)sN1;
    const bshort8* BD = (const bshort8*)sDec;
    u16* myP = (u16*)sT[wid];
    float* sD = sT[wid];

    bshort8 afh0 = *(const bshort8*)(hb + (size_t)n0 * 64 + half * 8);
    bshort8 afh1 = *(const bshort8*)(hb + (size_t)n0 * 64 + 32 + half * 8);
    bshort8 afs0 = *(const bshort8*)(Sb + (size_t)n0 * 64 + half * 8);
    bshort8 afs1 = *(const bshort8*)(Sb + (size_t)n0 * 64 + 32 + half * 8);
    bshort8 afd;
#pragma unroll
    for (int j = 0; j < 8; ++j) afd[j] = 0;
    if (half == 0) {
        float deg = (float)(start[n0 + 1] - start[n0]);
        afd[0] = (short)f2bu(deg);
    }
    f32x4 acc[4];
#pragma unroll
    for (int nt = 0; nt < 4; ++nt) {
        float b = b0[nt * 16 + m16];
        acc[nt] = f32x4{b, b, b, b};
    }
#pragma unroll
    for (int nt = 0; nt < 4; ++nt)
        acc[nt] = __builtin_amdgcn_mfma_f32_16x16x32_bf16(afh0, B0[nt * 64 + lane], acc[nt], 0, 0, 0);
#pragma unroll
    for (int nt = 0; nt < 4; ++nt)
        acc[nt] = __builtin_amdgcn_mfma_f32_16x16x32_bf16(afh1, B0[(4 + nt) * 64 + lane], acc[nt], 0, 0, 0);
#pragma unroll
    for (int nt = 0; nt < 4; ++nt)
        acc[nt] = __builtin_amdgcn_mfma_f32_16x16x32_bf16(afs0, B0[(8 + nt) * 64 + lane], acc[nt], 0, 0, 0);
#pragma unroll
    for (int nt = 0; nt < 4; ++nt)
        acc[nt] = __builtin_amdgcn_mfma_f32_16x16x32_bf16(afs1, B0[(12 + nt) * 64 + lane], acc[nt], 0, 0, 0);
#pragma unroll
    for (int nt = 0; nt < 4; ++nt)
        acc[nt] = __builtin_amdgcn_mfma_f32_16x16x32_bf16(afd, B0[(16 + nt) * 64 + lane], acc[nt], 0, 0, 0);
#pragma unroll
    for (int nt = 0; nt < 4; ++nt)
#pragma unroll
        for (int r = 0; r < 4; ++r) {
            float v = acc[nt][r];
            v = eluf(v);
            myP[(half * 4 + r) * 72 + nt * 16 + m16] = f2bu(v);
        }
    f32x4 acc2[4];
#pragma unroll
    for (int nt = 0; nt < 4; ++nt) {
        float b = b1[nt * 16 + m16];
        acc2[nt] = f32x4{b, b, b, b};
    }
#pragma unroll
    for (int ks = 0; ks < 2; ++ks) {
        bshort8 av = *(const bshort8*)(myP + m16 * 72 + ks * 32 + half * 8);
#pragma unroll
        for (int nt = 0; nt < 4; ++nt)
            acc2[nt] = __builtin_amdgcn_mfma_f32_16x16x32_bf16(
                av, B1[(ks * 4 + nt) * 64 + lane], acc2[nt], 0, 0, 0);
    }
    float nh[4][4];
#pragma unroll
    for (int nt = 0; nt < 4; ++nt)
#pragma unroll
        for (int r = 0; r < 4; ++r) {
            size_t ix = (size_t)(g * 16 + half * 4 + r) * 64 + nt * 16 + m16;
            nh[nt][r] = b2f_raw(hb[ix]) + acc2[nt][r];
        }
#pragma unroll
    for (int nt = 0; nt < 4; ++nt)
#pragma unroll
        for (int r = 0; r < 4; ++r)
            myP[(half * 4 + r) * 72 + nt * 16 + m16] = f2bu(nh[nt][r]);
    const float* db0 = wblk + OFF_DEC_B0;
    f32x4 acc3[4];
#pragma unroll
    for (int nt = 0; nt < 4; ++nt) {
        float b = db0[nt * 16 + m16];
        acc3[nt] = f32x4{b, b, b, b};
    }
#pragma unroll
    for (int ks = 0; ks < 2; ++ks) {
        bshort8 av = *(const bshort8*)(myP + m16 * 72 + ks * 32 + half * 8);
#pragma unroll
        for (int nt = 0; nt < 4; ++nt)
            acc3[nt] = __builtin_amdgcn_mfma_f32_16x16x32_bf16(
                av, BD[(ks * 4 + nt) * 64 + lane], acc3[nt], 0, 0, 0);
    }
#pragma unroll
    for (int nt = 0; nt < 4; ++nt)
#pragma unroll
        for (int r = 0; r < 4; ++r) {
            float v = acc3[nt][r];
            v = eluf(v);
            sD[(half * 4 + r) * 65 + nt * 16 + m16] = v;
        }
    if (lane < 48) {
        int j = lane / 3, o = lane - j * 3;
        const float* dW1 = wblk + OFF_DEC_W1;
        float oacc = wblk[OFF_DEC_B1 + o];
#pragma unroll
        for (int k = 0; k < 64; ++k) oacc += sD[j * 65 + k] * dW1[k * 3 + o];
        int nn = g * 16 + j;
        if (flags[0]) ((float*)out)[nn * 3 + o] = oacc;
        else          ((bf16*)out)[nn * 3 + o] = __float2bfloat16(oacc);
    }
}

extern "C" void kernel_launch(void* const* d_in, const int* in_sizes, int n_in,
                              void* d_out, int out_size, void* d_ws, size_t ws_size,
                              hipStream_t stream) {
    // Workspace (f32 words), total ~59 MB
    int*   flags   = (int*)d_ws;                        // 16
    float* wblk    = (float*)d_ws + 16;                 // 75392
    u16*   swz     = (u16*)(wblk + WBLK_WORDS);         // 61440 u16
    u16*   pos4b   = swz + SWZ_U16;                     // 400000 u16
    int*   gcursor = (int*)(pos4b + 400000);            // 512
    int*   gbase2  = gcursor + 512;                     // 512 (unused, layout kept)
    int*   start   = gbase2 + 512;                      // NN + 512
    int*   srcs    = start + NN + 512;                  // NE
    u16*   Sb      = (u16*)(srcs + NE);                 // NN*64 u16 (12.8 MB)
    u16*   hb      = Sb + (size_t)NN * 64;              // NN*64 u16 (12.8 MB)
    u16*   U       = hb + (size_t)NN * 64;              // NN*64 u16
    u16*   V       = U + (size_t)NN * 64;               // NN*64 u16
    u32*   epk_b   = (u32*)Sb;  // 391*4608 u32 = 7.2MB <= Sb 12.8MB; dead before edge_sum

    probe_kernel<<<1, 512, 0, stream>>>((const u16*)d_in[0],
                                        (const unsigned int*)d_in[2], flags, gcursor);

    WPtrs wp;
    wp.p[0] = d_in[3];  wp.p[1] = d_in[4];  wp.p[2] = d_in[5];  wp.p[3] = d_in[6];
    wp.p[4] = d_in[7];  wp.p[5] = d_in[8];  wp.p[6] = d_in[9];  wp.p[7] = d_in[10];
    wp.p[8] = d_in[11]; wp.p[9] = d_in[12]; wp.p[10] = d_in[13]; wp.p[11] = d_in[14];
    wp.p[12] = d_in[15]; wp.p[13] = d_in[16]; wp.p[14] = d_in[17]; wp.p[15] = d_in[18];
    canon_weights<<<dim3(98, 16), 256, 0, stream>>>(wp, wblk, flags);
    prep_wf<<<33, 256, 0, stream>>>(wblk);
    prep_swz<<<240, 256, 0, stream>>>(wblk, swz);

    passA_bin<<<(NE + 4095) / 4096, 1024, 0, stream>>>(d_in[2], flags, epk_b, gcursor);
    passB_sort<<<NBKT, 1024, 0, stream>>>(epk_b, gcursor, srcs, start);

    const int NODE_BLOCKS = (NN / 16 + 7) / 8;   // 782 (8 waves per block)
    const int EDGE_BLOCKS = 2048;
    const int TOTALWAVES = EDGE_BLOCKS * 4;

    enc_uv<<<NODE_BLOCKS, 512, 0, stream>>>(
        d_in[0], d_in[1], wblk, swz + SWZ_ENC,
        swz, swz + SWZ_V, hb, pos4b, U, V, flags);

    // layer 0
    edge_sum<<<EDGE_BLOCKS, 256, 0, stream>>>(
        (const u32*)U, (const u32*)V, srcs, start, (u32*)Sb, TOTALWAVES);
    node_uv<<<NODE_BLOCKS, 512, 0, stream>>>(
        hb, Sb, start, wblk, swz, pos4b, U, V);

    // layer 1
    edge_sum<<<EDGE_BLOCKS, 256, 0, stream>>>(
        (const u32*)U, (const u32*)V, srcs, start, (u32*)Sb, TOTALWAVES);
    node_dec<<<NODE_BLOCKS, 512, 0, stream>>>(
        hb, Sb, start, wblk, swz, d_out, flags);
}